// Round 8
// baseline (658.491 us; speedup 1.0000x reference)
//
#include <hip/hip_runtime.h>
#include <hip/hip_fp16.h>

#define BF 256
#define TSTEPS 256

typedef _Float16 h8_t __attribute__((ext_vector_type(8)));
typedef _Float16 h4_t __attribute__((ext_vector_type(4)));
typedef float f4_t __attribute__((ext_vector_type(4)));

union H8 { uint4 u; h8_t v; };
union H4 { uint2 u; h4_t v; };
union U2H4 { uint2 u; __half h[4]; };

static __device__ __forceinline__ float sigmoidf_(float x) {
    return 1.f / (1.f + __expf(-x));
}
static __device__ __forceinline__ float tanhf_(float x) {
    return 1.f - 2.f / (__expf(2.f * x) + 1.f);
}

// ---- pack helper: f16 MFMA operand layout -----------------------------------------
static __device__ __forceinline__ void pack_one(const float* __restrict__ src,
                                                __half* __restrict__ dst,
                                                int OC, int IC, int KS,
                                                int oc_str, int ic_str, int k_str, int i) {
    int grp = KS / 4;
    int j = i % grp;
    int oc = (i / grp) % OC;
    int g = (i / (grp * OC)) & 3;
    int chunk = i / (grp * OC * 4);
    int CPK = IC / KS;
    int cc = chunk % CPK;
    int khw = chunk / CPK;
    int ic = cc * KS + g * grp + j;
    dst[i] = __float2half(src[(long)oc * oc_str + (long)ic * ic_str + khw * k_str]);
}

// ---- fused weight prep ------------------------------------------------------------
__global__ __launch_bounds__(256) void prep_k(
        const float* __restrict__ w0, const float* __restrict__ w1,
        const float* __restrict__ w2, const float* __restrict__ w3,
        const float* __restrict__ Wihf, const float* __restrict__ Wihb,
        const float* __restrict__ Whhf, const float* __restrict__ Whhb,
        float* __restrict__ w0t, __half* __restrict__ w1p,
        __half* __restrict__ w2p, __half* __restrict__ w3p,
        __half* __restrict__ wfp, __half* __restrict__ wbp,
        __half* __restrict__ whhfp, __half* __restrict__ whhbp) {
    int i = blockIdx.x * 256 + threadIdx.x;
    if (i < 144) { int oc = i / 9, rem = i % 9; w0t[rem * 16 + oc] = w0[i]; return; }
    i -= 144;
    if (i < 4608) { pack_one(w1, w1p, 32, 16, 16, 144, 9, 1, i); return; }
    i -= 4608;
    if (i < 18432) { pack_one(w2, w2p, 64, 32, 32, 288, 9, 1, i); return; }
    i -= 18432;
    if (i < 73728) { pack_one(w3, w3p, 128, 64, 32, 576, 9, 1, i); return; }
    i -= 73728;
    if (i < 65536) { pack_one(Wihf, wfp, 512, 128, 32, 128, 1, 0, i); return; }
    i -= 65536;
    if (i < 65536) { pack_one(Wihb, wbp, 512, 128, 32, 128, 1, 0, i); return; }
    i -= 65536;
    if (i < 65536) { pack_one(Whhf, whhfp, 512, 128, 32, 128, 1, 0, i); return; }
    i -= 65536;
    if (i < 65536) { pack_one(Whhb, whhbp, 512, 128, 32, 128, 1, 0, i); return; }
}

__global__ void pack_wf16(const float* __restrict__ src, __half* __restrict__ dst,
                          int OC, int IC, int KS,
                          int oc_str, int ic_str, int k_str, int total) {
    int i = blockIdx.x * 256 + threadIdx.x;
    if (i >= total) return;
    pack_one(src, dst, OC, IC, KS, oc_str, ic_str, k_str, i);
}

// ---- conv0: 1->16 ch, VALU, NHWC f16 out ------------------------------------------
__global__ __launch_bounds__(256) void conv0_k(const float* __restrict__ in,
                                               const float* __restrict__ wT,
                                               const float* __restrict__ bias,
                                               __half* __restrict__ out) {
    __shared__ float wsm[9][16];
    __shared__ float bs[16];
    int tid = threadIdx.x;
    if (tid < 144) wsm[tid / 16][tid % 16] = wT[tid];
    if (tid < 16) bs[tid] = bias[tid];
    __syncthreads();
    int gid = blockIdx.x * 256 + tid;
    int ow = gid % 27;
    int t = (gid / 27) % 256;
    int bf = gid / (27 * 256);
    float acc[16];
#pragma unroll
    for (int o = 0; o < 16; o++) acc[o] = bs[o];
    int iw0 = ow * 3 - 1;
#pragma unroll
    for (int kh = 0; kh < 3; kh++) {
        int tt = t + kh - 1;
        if ((unsigned)tt >= 256u) continue;
        const float* ip = in + ((long)bf * 256 + tt) * 81;
#pragma unroll
        for (int kw = 0; kw < 3; kw++) {
            int iw = iw0 + kw;
            if ((unsigned)iw >= 81u) continue;
            float x = ip[iw];
#pragma unroll
            for (int o = 0; o < 16; o++) acc[o] += x * wsm[kh * 3 + kw][o];
        }
    }
    __half2* op = (__half2*)(out + (long)gid * 16);
#pragma unroll
    for (int o = 0; o < 8; o++)
        op[o] = __floats2half2_rn(fmaxf(acc[2 * o], 0.f), fmaxf(acc[2 * o + 1], 0.f));
}

// ---- MFMA implicit-GEMM conv: NHWC f16 in/out -------------------------------------
template<int IC, int OC, int WIN, int WOUT, int KS>
__global__ __launch_bounds__(256) void convM_k(const __half* __restrict__ in,
                                               const __half* __restrict__ wp,
                                               const float* __restrict__ bias,
                                               __half* __restrict__ out) {
    constexpr int NT = OC / 16;
    constexpr int CPK = IC / KS;
    constexpr int NCHUNK = 9 * CPK;
    constexpr int GRP = KS / 4;
    int tid = threadIdx.x;
    int lane = tid & 63;
    int wv = tid >> 6;
    int l15 = lane & 15;
    int g = lane >> 4;
    int m = blockIdx.x * 64 + wv * 16 + l15;
    int ow = m % WOUT;
    int t = (m / WOUT) % 256;
    int bf = m / (WOUT * 256);

    f4_t acc[NT];
#pragma unroll
    for (int nt = 0; nt < NT; nt++)
#pragma unroll
        for (int r = 0; r < 4; r++) acc[nt][r] = 0.f;

#pragma unroll
    for (int chunk = 0; chunk < NCHUNK; chunk++) {
        int khw = chunk / CPK, cc = chunk % CPK;
        int kh = khw / 3;
        int kw = khw - kh * 3;
        int tt = t + kh - 1;
        int iw = ow * 3 + kw - 1;
        bool ok = ((unsigned)tt < 256u) && ((unsigned)iw < (unsigned)WIN);
        long aoff = ok ? (((long)(bf * 256 + tt) * WIN + iw) * IC + cc * KS + g * GRP) : 0;
        if constexpr (KS == 32) {
            H8 af;
            af.u = *(const uint4*)(in + aoff);
            if (!ok) af.u = make_uint4(0u, 0u, 0u, 0u);
#pragma unroll
            for (int nt = 0; nt < NT; nt++) {
                H8 bf8;
                bf8.u = *(const uint4*)(wp + ((long)(chunk * 4 + g) * OC + nt * 16 + l15) * GRP);
                acc[nt] = __builtin_amdgcn_mfma_f32_16x16x32_f16(af.v, bf8.v, acc[nt], 0, 0, 0);
            }
        } else {
            H4 af;
            af.u = *(const uint2*)(in + aoff);
            if (!ok) af.u = make_uint2(0u, 0u);
#pragma unroll
            for (int nt = 0; nt < NT; nt++) {
                H4 bf4;
                bf4.u = *(const uint2*)(wp + ((long)(chunk * 4 + g) * OC + nt * 16 + l15) * GRP);
                acc[nt] = __builtin_amdgcn_mfma_f32_16x16x16f16(af.v, bf4.v, acc[nt], 0, 0, 0);
            }
        }
    }
    int orow = blockIdx.x * 64 + wv * 16 + g * 4;
#pragma unroll
    for (int nt = 0; nt < NT; nt++) {
        int oc = nt * 16 + l15;
        float b = bias[oc];
#pragma unroll
        for (int r = 0; r < 4; r++) {
            float v = fmaxf(acc[nt][r] + b, 0.f);
            out[(long)(orow + r) * OC + oc] = __float2half(v);
        }
    }
}

// ---- gates MFMA GEMM, TRANSPOSED output G'[(b*512+gate)*256 + tidx] ---------------
// fwd: tidx = t ; bwd: tidx = 255 - t (so lstm always reads ascending tidx)
__global__ __launch_bounds__(256) void gates_k(const __half* __restrict__ X,
                                               const __half* __restrict__ wpf,
                                               const __half* __restrict__ wpb,
                                               const float* __restrict__ bf1,
                                               const float* __restrict__ bf2,
                                               const float* __restrict__ bb1,
                                               const float* __restrict__ bb2,
                                               __half* __restrict__ Gf,
                                               __half* __restrict__ Gb) {
    int dir = blockIdx.z;
    const __half* wp = dir ? wpb : wpf;
    const float* b1 = dir ? bb1 : bf1;
    const float* b2 = dir ? bb2 : bf2;
    __half* G = dir ? Gb : Gf;
    int tid = threadIdx.x;
    int lane = tid & 63;
    int wv = tid >> 6;
    int l15 = lane & 15;
    int g = lane >> 4;
    long r0 = (long)blockIdx.x * 128 + wv * 32;
    int n0 = blockIdx.y * 128;

    f4_t acc[2][8];
#pragma unroll
    for (int s = 0; s < 2; s++)
#pragma unroll
        for (int nt = 0; nt < 8; nt++)
#pragma unroll
            for (int r = 0; r < 4; r++) acc[s][nt][r] = 0.f;

#pragma unroll
    for (int chunk = 0; chunk < 4; chunk++) {
        H8 a0, a1;
        a0.u = *(const uint4*)(X + (r0 + l15) * 128 + chunk * 32 + g * 8);
        a1.u = *(const uint4*)(X + (r0 + 16 + l15) * 128 + chunk * 32 + g * 8);
#pragma unroll
        for (int nt = 0; nt < 8; nt++) {
            H8 bw;
            bw.u = *(const uint4*)(wp + ((long)(chunk * 4 + g) * 512 + n0 + nt * 16 + l15) * 8);
            acc[0][nt] = __builtin_amdgcn_mfma_f32_16x16x32_f16(a0.v, bw.v, acc[0][nt], 0, 0, 0);
            acc[1][nt] = __builtin_amdgcn_mfma_f32_16x16x32_f16(a1.v, bw.v, acc[1][nt], 0, 0, 0);
        }
    }
    int b = (int)(r0 >> 8);
#pragma unroll
    for (int nt = 0; nt < 8; nt++) {
        int col = n0 + nt * 16 + l15;
        float bias = b1[col] + b2[col];
        long base = ((long)b * 512 + col) * 256;
#pragma unroll
        for (int s = 0; s < 2; s++) {
            int tb = (int)(r0 & 255) + s * 16 + g * 4;
            U2H4 pk;
            if (!dir) {
#pragma unroll
                for (int r = 0; r < 4; r++) pk.h[r] = __float2half(acc[s][nt][r] + bias);
                *(uint2*)(G + base + tb) = pk.u;
            } else {
#pragma unroll
                for (int r = 0; r < 4; r++) pk.h[3 - r] = __float2half(acc[s][nt][r] + bias);
                *(uint2*)(G + base + (252 - tb)) = pk.u;
            }
        }
    }
}

// ---- LSTM recurrence: 512 blocks x 512 thr, 1 chain/block (2 blocks/CU) -----------
// Wave w owns units w*16..w*16+15 for all 4 gate classes; N = 16 replicas of the
// chain. bit2 splits classes {i,f}/{g,o}; shfl_xor(4) stitches the cell update.
__global__ __launch_bounds__(512, 2) void lstm_k(const __half* __restrict__ Gf,
                                                 const __half* __restrict__ Gb,
                                                 const __half* __restrict__ whhfp,
                                                 const __half* __restrict__ whhbp,
                                                 __half* __restrict__ flat) {
    int bid = blockIdx.x;
    int dir = bid >> 8;
    int bq = bid & 255;
    const __half* G = dir ? Gb : Gf;
    const __half* wp = dir ? whhbp : whhfp;
    int tid = threadIdx.x;
    int w = tid >> 6;
    int lane = tid & 63;
    int l15 = lane & 15;
    int g2 = lane >> 4;
    int r = l15 & 3;
    int bit2 = (l15 >> 2) & 1;
    int ua = w * 16 + g2 * 4 + r;
    bool wrt = bit2 && ((r & 1) == 0) && (l15 < 8);

    // Whh A-frags: 4 classes x 4 k-chunks = 64 VGPRs/lane
    H8 afr[4][4];
#pragma unroll
    for (int k = 0; k < 4; k++) {
        int gate = k * 128 + w * 16 + l15;
#pragma unroll
        for (int c = 0; c < 4; c++)
            afr[k][c].u = *(const uint4*)(wp + ((long)((c * 4 + g2) * 512 + gate)) * 8);
    }

    __shared__ __align__(16) __half hbuf[2][128];
    if (tid < 128) hbuf[0][tid] = __float2half(0.f);
    __syncthreads();

    // this lane's two gate-class rows in transposed G; 8 steps per 16B load
    const __half* gb0 = G + (((long)bq * 512) + bit2 * 256 + ua) * 256;
    const __half* gb1 = gb0 + 128 * 256;

    float cst = 0.f;
    float ma = bit2 ? 2.f : 1.f;
    float mb = bit2 ? 2.f : 1.f;
    float cb = bit2 ? -1.f : 0.f;
    const f4_t zero4 = {0.f, 0.f, 0.f, 0.f};

    H8 gc0, gc1, gn0, gn1;
    gc0.u = *(const uint4*)(gb0);
    gc1.u = *(const uint4*)(gb1);
    long fbase = (long)bq * 65536 + dir * 128 + ua;

    for (int to = 0; to < 32; to++) {
        if (to < 31) {
            gn0.u = *(const uint4*)(gb0 + (to + 1) * 8);
            gn1.u = *(const uint4*)(gb1 + (to + 1) * 8);
        }
#pragma unroll
        for (int ti = 0; ti < 8; ti++) {
            int s = to * 8 + ti;
            int p = s & 1;
            H8 bfr[4];
#pragma unroll
            for (int c = 0; c < 4; c++)
                bfr[c].u = *(const uint4*)(&hbuf[p][c * 32 + g2 * 8]);

            f4_t acc[4];
#pragma unroll
            for (int k = 0; k < 4; k++)
                acc[k] = __builtin_amdgcn_mfma_f32_16x16x32_f16(afr[k][0].v, bfr[0].v,
                                                                zero4, 0, 0, 0);
#pragma unroll
            for (int c = 1; c < 4; c++)
#pragma unroll
                for (int k = 0; k < 4; k++)
                    acc[k] = __builtin_amdgcn_mfma_f32_16x16x32_f16(afr[k][c].v, bfr[c].v,
                                                                    acc[k], 0, 0, 0);
            f4_t aA, aB;
#pragma unroll
            for (int e = 0; e < 4; e++) {
                aA[e] = bit2 ? acc[2][e] : acc[0][e];
                aB[e] = bit2 ? acc[3][e] : acc[1][e];
            }
            float loA = (r & 1) ? aA[1] : aA[0];
            float hiA = (r & 1) ? aA[3] : aA[2];
            float eA = (r & 2) ? hiA : loA;
            float loB = (r & 1) ? aB[1] : aB[0];
            float hiB = (r & 1) ? aB[3] : aB[2];
            float eB = (r & 2) ? hiB : loB;

            float za = eA + (float)gc0.v[ti];
            float zb = eB + (float)gc1.v[ti];
            float sa = sigmoidf_(ma * za);
            float fa = sa * mb + cb;            // bit2=0: sigmoid(i); bit2=1: tanh(g)
            float sb = sigmoidf_(zb);           // bit2=0: sigmoid(f); bit2=1: sigmoid(o)
            float grecv = __shfl_xor(fa, 4, 64);
            float cn = sb * cst + fa * grecv;   // valid on bit2=0 lanes
            cst = cn;
            float tc = tanhf_(cn);
            float tcr = __shfl_xor(tc, 4, 64);  // bit2=1 receives tanh(c')
            float h = sb * tcr;                 // valid on bit2=1 lanes
            float hp = __shfl_xor(h, 1, 64);    // partner unit's h
            if (wrt) {
                __half2 h2 = __floats2half2_rn(h, hp);
                int ts = dir ? (255 - s) : s;
                *(__half2*)(&hbuf[p ^ 1][ua]) = h2;
                *(__half2*)(flat + fbase + (long)ts * 256) = h2;
            }
            __syncthreads();
        }
        gc0 = gn0;
        gc1 = gn1;
    }
}

// ---- FC1 MFMA split-K: z[256][128] += flat16 @ fc1_w16^T --------------------------
__global__ __launch_bounds__(256) void fc1m_k(const __half* __restrict__ flat,
                                              const __half* __restrict__ wp,
                                              float* __restrict__ z) {
    int tid = threadIdx.x;
    int lane = tid & 63;
    int wv = tid >> 6;
    int l15 = lane & 15;
    int g = lane >> 4;
    int m0 = blockIdx.x * 64 + wv * 16;
    long k0 = (long)blockIdx.y * 1024;

    f4_t acc[8];
#pragma unroll
    for (int nt = 0; nt < 8; nt++)
#pragma unroll
        for (int r = 0; r < 4; r++) acc[nt][r] = 0.f;

    for (int c = 0; c < 32; c++) {
        long chunk = (k0 >> 5) + c;
        H8 af;
        af.u = *(const uint4*)(flat + (long)(m0 + l15) * 65536 + k0 + c * 32 + g * 8);
#pragma unroll
        for (int nt = 0; nt < 8; nt++) {
            H8 bw;
            bw.u = *(const uint4*)(wp + ((chunk * 4 + g) * 128 + nt * 16 + l15) * 8);
            acc[nt] = __builtin_amdgcn_mfma_f32_16x16x32_f16(af.v, bw.v, acc[nt], 0, 0, 0);
        }
    }
#pragma unroll
    for (int nt = 0; nt < 8; nt++)
#pragma unroll
        for (int r = 0; r < 4; r++)
            atomicAdd(&z[(m0 + g * 4 + r) * 128 + nt * 16 + l15], acc[nt][r]);
}

__global__ void zero_k(float* __restrict__ p, int n) {
    int i = blockIdx.x * 256 + threadIdx.x;
    if (i < n) p[i] = 0.f;
}

// ---- head -------------------------------------------------------------------------
__global__ __launch_bounds__(256) void head_k(const float* __restrict__ z,
                                              const float* __restrict__ b1,
                                              const float* __restrict__ fsw,
                                              const float* __restrict__ fsb,
                                              float* __restrict__ out) {
    __shared__ float sf[256];
    int r = threadIdx.x;
    float acc = fsb[0];
#pragma unroll
    for (int j4 = 0; j4 < 32; j4++) {
        float4 zv = *(const float4*)&z[r * 128 + j4 * 4];
        float4 bv = *(const float4*)&b1[j4 * 4];
        float4 wv = *(const float4*)&fsw[j4 * 4];
        acc += fmaxf(zv.x + bv.x, 0.f) * wv.x;
        acc += fmaxf(zv.y + bv.y, 0.f) * wv.y;
        acc += fmaxf(zv.z + bv.z, 0.f) * wv.z;
        acc += fmaxf(zv.w + bv.w, 0.f) * wv.w;
    }
    float val = sigmoidf_(acc) * 4.f + 1.f;
    out[16 + r] = val;
    sf[r] = val;
    __syncthreads();
    if (r < 16) {
        float m = 0.f;
#pragma unroll
        for (int f = 0; f < 16; f++) m += sf[r * 16 + f];
        out[r] = m * (1.f / 16.f);
    }
}

extern "C" void kernel_launch(void* const* d_in, const int* in_sizes, int n_in,
                              void* d_out, int out_size, void* d_ws, size_t ws_size,
                              hipStream_t stream) {
    const float* audio = (const float*)d_in[0];
    const float* w0 = (const float*)d_in[2];
    const float* b0 = (const float*)d_in[3];
    const float* w1 = (const float*)d_in[4];
    const float* b1 = (const float*)d_in[5];
    const float* w2 = (const float*)d_in[6];
    const float* b2 = (const float*)d_in[7];
    const float* w3 = (const float*)d_in[8];
    const float* b3 = (const float*)d_in[9];
    const float* Wih_f = (const float*)d_in[10];
    const float* Whh_f = (const float*)d_in[11];
    const float* bih_f = (const float*)d_in[12];
    const float* bhh_f = (const float*)d_in[13];
    const float* Wih_b = (const float*)d_in[14];
    const float* Whh_b = (const float*)d_in[15];
    const float* bih_b = (const float*)d_in[16];
    const float* bhh_b = (const float*)d_in[17];
    const float* fc1_w = (const float*)d_in[18];
    const float* fc1_b = (const float*)d_in[19];
    const float* fs_w = (const float*)d_in[20];
    const float* fs_b = (const float*)d_in[21];
    float* out = (float*)d_out;

    char* ws = (char*)d_ws;
    // lifetimes: out1 dies before Gf; out0 dies before flat16; Gf/Gb die before fc1p
    __half* Gf    = (__half*)(ws);                    // 67.1 MB (transposed layout)
    __half* out1  = (__half*)(ws);                    // 37.7 MB (pre-Gf)
    __half* fc1p  = (__half*)(ws);                    // 16.8 MB (post-lstm, in Gf)
    __half* Gb    = (__half*)(ws + 67108864);         // 67.1 MB
    __half* flat16= (__half*)(ws + 134217728);        // 33.6 MB
    __half* out0  = (__half*)(ws + 134217728);        // 56.6 MB (pre-flat16)
    __half* X     = (__half*)(ws + 201326592);        // 16.8 MB
    __half* out2  = (__half*)(ws + 218103808);        // 25.2 MB
    char* rd = ws + 243269632;
    float*  w0t   = (float*)(rd);
    __half* w1p   = (__half*)(rd + 1024);
    __half* w2p   = (__half*)(rd + 10240);
    __half* w3p   = (__half*)(rd + 47104);
    __half* wfp   = (__half*)(rd + 194560);
    __half* wbp   = (__half*)(rd + 325632);
    __half* whhfp = (__half*)(rd + 456704);
    __half* whhbp = (__half*)(rd + 587776);
    float*  zbuf  = (float*)(rd + 718848);

    // fused weight prep (1 launch)
    prep_k<<<1403, 256, 0, stream>>>(w0, w1, w2, w3, Wih_f, Wih_b, Whh_f, Whh_b,
                                     w0t, w1p, w2p, w3p, wfp, wbp, whhfp, whhbp);

    // conv chain (NHWC f16)
    conv0_k<<<6912, 256, 0, stream>>>(audio, w0t, b0, out0);
    convM_k<16, 32, 27, 9, 16><<<9216, 256, 0, stream>>>(out0, w1p, b1, out1);
    convM_k<32, 64, 9, 3, 32><<<3072, 256, 0, stream>>>(out1, w2p, b2, out2);
    convM_k<64, 128, 3, 1, 32><<<1024, 256, 0, stream>>>(out2, w3p, b3, X);

    // gates, both directions, transposed G output
    gates_k<<<dim3(512, 4, 2), 256, 0, stream>>>(X, wfp, wbp, bih_f, bhh_f,
                                                 bih_b, bhh_b, Gf, Gb);

    // recurrence (1 chain/block, 2 blocks/CU for latency overlap)
    lstm_k<<<512, 512, 0, stream>>>(Gf, Gb, whhfp, whhbp, flat16);

    // FC head: pack fc1_w (into dead Gf region), split-K MFMA, head
    pack_wf16<<<32768, 256, 0, stream>>>(fc1_w, fc1p, 128, 65536, 32, 65536, 1, 0, 8388608);
    zero_k<<<128, 256, 0, stream>>>(zbuf, 256 * 128);
    fc1m_k<<<dim3(4, 64), 256, 0, stream>>>(flat16, fc1p, zbuf);
    head_k<<<1, 256, 0, stream>>>(zbuf, fc1_b, fs_w, fs_b, out);
}

// Round 9
// 553.926 us; speedup vs baseline: 1.1888x; 1.1888x over previous
//
#include <hip/hip_runtime.h>
#include <hip/hip_fp16.h>

#define BF 256
#define TSTEPS 256

typedef _Float16 h8_t __attribute__((ext_vector_type(8)));
typedef _Float16 h4_t __attribute__((ext_vector_type(4)));
typedef float f4_t __attribute__((ext_vector_type(4)));

union H8 { uint4 u; h8_t v; };
union H4 { uint2 u; h4_t v; };
union U2H4 { uint2 u; __half h[4]; };

static __device__ __forceinline__ float sigmoidf_(float x) {
    return 1.f / (1.f + __expf(-x));
}
static __device__ __forceinline__ float tanhf_(float x) {
    return 1.f - 2.f / (__expf(2.f * x) + 1.f);
}

// ---- pack helper: f16 MFMA operand layout -----------------------------------------
static __device__ __forceinline__ void pack_one(const float* __restrict__ src,
                                                __half* __restrict__ dst,
                                                int OC, int IC, int KS,
                                                int oc_str, int ic_str, int k_str, int i) {
    int grp = KS / 4;
    int j = i % grp;
    int oc = (i / grp) % OC;
    int g = (i / (grp * OC)) & 3;
    int chunk = i / (grp * OC * 4);
    int CPK = IC / KS;
    int cc = chunk % CPK;
    int khw = chunk / CPK;
    int ic = cc * KS + g * grp + j;
    dst[i] = __float2half(src[(long)oc * oc_str + (long)ic * ic_str + khw * k_str]);
}

// ---- fused weight prep ------------------------------------------------------------
__global__ __launch_bounds__(256) void prep_k(
        const float* __restrict__ w0, const float* __restrict__ w1,
        const float* __restrict__ w2, const float* __restrict__ w3,
        const float* __restrict__ Wihf, const float* __restrict__ Wihb,
        const float* __restrict__ Whhf, const float* __restrict__ Whhb,
        float* __restrict__ w0t, __half* __restrict__ w1p,
        __half* __restrict__ w2p, __half* __restrict__ w3p,
        __half* __restrict__ wfp, __half* __restrict__ wbp,
        __half* __restrict__ whhfp, __half* __restrict__ whhbp) {
    int i = blockIdx.x * 256 + threadIdx.x;
    if (i < 144) { int oc = i / 9, rem = i % 9; w0t[rem * 16 + oc] = w0[i]; return; }
    i -= 144;
    if (i < 4608) { pack_one(w1, w1p, 32, 16, 16, 144, 9, 1, i); return; }
    i -= 4608;
    if (i < 18432) { pack_one(w2, w2p, 64, 32, 32, 288, 9, 1, i); return; }
    i -= 18432;
    if (i < 73728) { pack_one(w3, w3p, 128, 64, 32, 576, 9, 1, i); return; }
    i -= 73728;
    if (i < 65536) { pack_one(Wihf, wfp, 512, 128, 32, 128, 1, 0, i); return; }
    i -= 65536;
    if (i < 65536) { pack_one(Wihb, wbp, 512, 128, 32, 128, 1, 0, i); return; }
    i -= 65536;
    if (i < 65536) { pack_one(Whhf, whhfp, 512, 128, 32, 128, 1, 0, i); return; }
    i -= 65536;
    if (i < 65536) { pack_one(Whhb, whhbp, 512, 128, 32, 128, 1, 0, i); return; }
}

__global__ void pack_wf16(const float* __restrict__ src, __half* __restrict__ dst,
                          int OC, int IC, int KS,
                          int oc_str, int ic_str, int k_str, int total) {
    int i = blockIdx.x * 256 + threadIdx.x;
    if (i >= total) return;
    pack_one(src, dst, OC, IC, KS, oc_str, ic_str, k_str, i);
}

// ---- conv0: 1->16 ch, VALU, NHWC f16 out ------------------------------------------
__global__ __launch_bounds__(256) void conv0_k(const float* __restrict__ in,
                                               const float* __restrict__ wT,
                                               const float* __restrict__ bias,
                                               __half* __restrict__ out) {
    __shared__ float wsm[9][16];
    __shared__ float bs[16];
    int tid = threadIdx.x;
    if (tid < 144) wsm[tid / 16][tid % 16] = wT[tid];
    if (tid < 16) bs[tid] = bias[tid];
    __syncthreads();
    int gid = blockIdx.x * 256 + tid;
    int ow = gid % 27;
    int t = (gid / 27) % 256;
    int bf = gid / (27 * 256);
    float acc[16];
#pragma unroll
    for (int o = 0; o < 16; o++) acc[o] = bs[o];
    int iw0 = ow * 3 - 1;
#pragma unroll
    for (int kh = 0; kh < 3; kh++) {
        int tt = t + kh - 1;
        if ((unsigned)tt >= 256u) continue;
        const float* ip = in + ((long)bf * 256 + tt) * 81;
#pragma unroll
        for (int kw = 0; kw < 3; kw++) {
            int iw = iw0 + kw;
            if ((unsigned)iw >= 81u) continue;
            float x = ip[iw];
#pragma unroll
            for (int o = 0; o < 16; o++) acc[o] += x * wsm[kh * 3 + kw][o];
        }
    }
    __half2* op = (__half2*)(out + (long)gid * 16);
#pragma unroll
    for (int o = 0; o < 8; o++)
        op[o] = __floats2half2_rn(fmaxf(acc[2 * o], 0.f), fmaxf(acc[2 * o + 1], 0.f));
}

// ---- MFMA implicit-GEMM conv: NHWC f16 in/out -------------------------------------
template<int IC, int OC, int WIN, int WOUT, int KS>
__global__ __launch_bounds__(256) void convM_k(const __half* __restrict__ in,
                                               const __half* __restrict__ wp,
                                               const float* __restrict__ bias,
                                               __half* __restrict__ out) {
    constexpr int NT = OC / 16;
    constexpr int CPK = IC / KS;
    constexpr int NCHUNK = 9 * CPK;
    constexpr int GRP = KS / 4;
    int tid = threadIdx.x;
    int lane = tid & 63;
    int wv = tid >> 6;
    int l15 = lane & 15;
    int g = lane >> 4;
    int m = blockIdx.x * 64 + wv * 16 + l15;
    int ow = m % WOUT;
    int t = (m / WOUT) % 256;
    int bf = m / (WOUT * 256);

    f4_t acc[NT];
#pragma unroll
    for (int nt = 0; nt < NT; nt++)
#pragma unroll
        for (int r = 0; r < 4; r++) acc[nt][r] = 0.f;

#pragma unroll
    for (int chunk = 0; chunk < NCHUNK; chunk++) {
        int khw = chunk / CPK, cc = chunk % CPK;
        int kh = khw / 3;
        int kw = khw - kh * 3;
        int tt = t + kh - 1;
        int iw = ow * 3 + kw - 1;
        bool ok = ((unsigned)tt < 256u) && ((unsigned)iw < (unsigned)WIN);
        long aoff = ok ? (((long)(bf * 256 + tt) * WIN + iw) * IC + cc * KS + g * GRP) : 0;
        if constexpr (KS == 32) {
            H8 af;
            af.u = *(const uint4*)(in + aoff);
            if (!ok) af.u = make_uint4(0u, 0u, 0u, 0u);
#pragma unroll
            for (int nt = 0; nt < NT; nt++) {
                H8 bf8;
                bf8.u = *(const uint4*)(wp + ((long)(chunk * 4 + g) * OC + nt * 16 + l15) * GRP);
                acc[nt] = __builtin_amdgcn_mfma_f32_16x16x32_f16(af.v, bf8.v, acc[nt], 0, 0, 0);
            }
        } else {
            H4 af;
            af.u = *(const uint2*)(in + aoff);
            if (!ok) af.u = make_uint2(0u, 0u);
#pragma unroll
            for (int nt = 0; nt < NT; nt++) {
                H4 bf4;
                bf4.u = *(const uint2*)(wp + ((long)(chunk * 4 + g) * OC + nt * 16 + l15) * GRP);
                acc[nt] = __builtin_amdgcn_mfma_f32_16x16x16f16(af.v, bf4.v, acc[nt], 0, 0, 0);
            }
        }
    }
    int orow = blockIdx.x * 64 + wv * 16 + g * 4;
#pragma unroll
    for (int nt = 0; nt < NT; nt++) {
        int oc = nt * 16 + l15;
        float b = bias[oc];
#pragma unroll
        for (int r = 0; r < 4; r++) {
            float v = fmaxf(acc[nt][r] + b, 0.f);
            out[(long)(orow + r) * OC + oc] = __float2half(v);
        }
    }
}

// ---- gates MFMA GEMM, TRANSPOSED output G'[(b*512+gate)*256 + tidx] ---------------
// fwd: tidx = t ; bwd: tidx = 255 - t (so lstm always reads ascending tidx)
__global__ __launch_bounds__(256) void gates_k(const __half* __restrict__ X,
                                               const __half* __restrict__ wpf,
                                               const __half* __restrict__ wpb,
                                               const float* __restrict__ bf1,
                                               const float* __restrict__ bf2,
                                               const float* __restrict__ bb1,
                                               const float* __restrict__ bb2,
                                               __half* __restrict__ Gf,
                                               __half* __restrict__ Gb) {
    int dir = blockIdx.z;
    const __half* wp = dir ? wpb : wpf;
    const float* b1 = dir ? bb1 : bf1;
    const float* b2 = dir ? bb2 : bf2;
    __half* G = dir ? Gb : Gf;
    int tid = threadIdx.x;
    int lane = tid & 63;
    int wv = tid >> 6;
    int l15 = lane & 15;
    int g = lane >> 4;
    long r0 = (long)blockIdx.x * 128 + wv * 32;
    int n0 = blockIdx.y * 128;

    f4_t acc[2][8];
#pragma unroll
    for (int s = 0; s < 2; s++)
#pragma unroll
        for (int nt = 0; nt < 8; nt++)
#pragma unroll
            for (int r = 0; r < 4; r++) acc[s][nt][r] = 0.f;

#pragma unroll
    for (int chunk = 0; chunk < 4; chunk++) {
        H8 a0, a1;
        a0.u = *(const uint4*)(X + (r0 + l15) * 128 + chunk * 32 + g * 8);
        a1.u = *(const uint4*)(X + (r0 + 16 + l15) * 128 + chunk * 32 + g * 8);
#pragma unroll
        for (int nt = 0; nt < 8; nt++) {
            H8 bw;
            bw.u = *(const uint4*)(wp + ((long)(chunk * 4 + g) * 512 + n0 + nt * 16 + l15) * 8);
            acc[0][nt] = __builtin_amdgcn_mfma_f32_16x16x32_f16(a0.v, bw.v, acc[0][nt], 0, 0, 0);
            acc[1][nt] = __builtin_amdgcn_mfma_f32_16x16x32_f16(a1.v, bw.v, acc[1][nt], 0, 0, 0);
        }
    }
    int b = (int)(r0 >> 8);
#pragma unroll
    for (int nt = 0; nt < 8; nt++) {
        int col = n0 + nt * 16 + l15;
        float bias = b1[col] + b2[col];
        long base = ((long)b * 512 + col) * 256;
#pragma unroll
        for (int s = 0; s < 2; s++) {
            int tb = (int)(r0 & 255) + s * 16 + g * 4;
            U2H4 pk;
            if (!dir) {
#pragma unroll
                for (int r = 0; r < 4; r++) pk.h[r] = __float2half(acc[s][nt][r] + bias);
                *(uint2*)(G + base + tb) = pk.u;
            } else {
#pragma unroll
                for (int r = 0; r < 4; r++) pk.h[3 - r] = __float2half(acc[s][nt][r] + bias);
                *(uint2*)(G + base + (252 - tb)) = pk.u;
            }
        }
    }
}

// ---- LSTM recurrence: 256 blocks x 512 thr, 2 chains/block ------------------------
// Inner 16-step groups have NO global memory ops: G staged in registers per group,
// h history in a 16-row LDS window (chain stride 160 halves -> disjoint banks),
// flat flushed once per group (1 vmcnt drain / 16 steps).
__global__ __launch_bounds__(512, 2) void lstm_k(const __half* __restrict__ Gf,
                                                 const __half* __restrict__ Gb,
                                                 const __half* __restrict__ whhfp,
                                                 const __half* __restrict__ whhbp,
                                                 __half* __restrict__ flat) {
    int bid = blockIdx.x;
    int dir = bid >> 7;
    int b0 = (bid & 127) * 2;
    const __half* G = dir ? Gb : Gf;
    const __half* wp = dir ? whhbp : whhfp;
    int tid = threadIdx.x;
    int w = tid >> 6;
    int lane = tid & 63;
    int l15 = lane & 15;
    int g2 = lane >> 4;
    int chn = l15 >> 3;
    int r = l15 & 3;
    int bit2 = (l15 >> 2) & 1;
    int ua = w * 16 + g2 * 4 + r;
    bool wrt = bit2 && ((r & 1) == 0);

    // Whh A-frags: 4 classes x 4 k-chunks = 64 regs/lane
    H8 afr[4][4];
#pragma unroll
    for (int k = 0; k < 4; k++) {
        int gate = k * 128 + w * 16 + l15;
#pragma unroll
        for (int c = 0; c < 4; c++)
            afr[k][c].u = *(const uint4*)(wp + ((long)((c * 4 + g2) * 512 + gate)) * 8);
    }

    // 16-step h window; chain stride 160 halves (80 words = 16 banks) -> no conflicts
    __shared__ __align__(16) __half hist[16][320];
    if (tid < 160) { hist[15][tid] = __float2half(0.f);
                     hist[15][160 + tid] = __float2half(0.f); }
    __syncthreads();

    // this lane's two gate-class rows in transposed G
    const __half* gp0 = G + (((long)(b0 + chn) * 512) + bit2 * 256 + ua) * 256;
    const __half* gp1 = gp0 + 128 * 256;

    float cst = 0.f;
    float ma = bit2 ? 2.f : 1.f;
    float mb = ma;
    float cb = bit2 ? -1.f : 0.f;
    const f4_t zero4 = {0.f, 0.f, 0.f, 0.f};

    for (int go = 0; go < 16; go++) {
        // stage this group's 16 gate pre-activations per class (registers)
        H8 gA0, gA1, gB0, gB1;
        gA0.u = *(const uint4*)(gp0 + go * 16);
        gA1.u = *(const uint4*)(gp0 + go * 16 + 8);
        gB0.u = *(const uint4*)(gp1 + go * 16);
        gB1.u = *(const uint4*)(gp1 + go * 16 + 8);

#pragma unroll
        for (int j = 0; j < 16; j++) {
            int rs = (j + 15) & 15;
            H8 bfr[4];
#pragma unroll
            for (int c = 0; c < 4; c++)
                bfr[c].u = *(const uint4*)(&hist[rs][chn * 160 + c * 32 + g2 * 8]);

            f4_t acc[4];
#pragma unroll
            for (int k = 0; k < 4; k++)
                acc[k] = __builtin_amdgcn_mfma_f32_16x16x32_f16(afr[k][0].v, bfr[0].v,
                                                                zero4, 0, 0, 0);
#pragma unroll
            for (int c = 1; c < 4; c++)
#pragma unroll
                for (int k = 0; k < 4; k++)
                    acc[k] = __builtin_amdgcn_mfma_f32_16x16x32_f16(afr[k][c].v, bfr[c].v,
                                                                    acc[k], 0, 0, 0);
            f4_t aA, aB;
#pragma unroll
            for (int e = 0; e < 4; e++) {
                aA[e] = bit2 ? acc[2][e] : acc[0][e];
                aB[e] = bit2 ? acc[3][e] : acc[1][e];
            }
            float loA = (r & 1) ? aA[1] : aA[0];
            float hiA = (r & 1) ? aA[3] : aA[2];
            float eA = (r & 2) ? hiA : loA;
            float loB = (r & 1) ? aB[1] : aB[0];
            float hiB = (r & 1) ? aB[3] : aB[2];
            float eB = (r & 2) ? hiB : loB;

            float ga = (float)((j < 8) ? gA0.v[j & 7] : gA1.v[j & 7]);
            float gb = (float)((j < 8) ? gB0.v[j & 7] : gB1.v[j & 7]);
            float za = eA + ga;
            float zb = eB + gb;
            float sa = sigmoidf_(ma * za);
            float fa = sa * mb + cb;            // bit2=0: sigmoid(i); bit2=1: tanh(g)
            float sb = sigmoidf_(zb);           // bit2=0: sigmoid(f); bit2=1: sigmoid(o)
            float grecv = __shfl_xor(fa, 4, 64);
            float cn = sb * cst + fa * grecv;   // valid on bit2=0 lanes
            cst = cn;
            float tc = tanhf_(cn);
            float tcr = __shfl_xor(tc, 4, 64);  // bit2=1 receives tanh(c')
            float h = sb * tcr;                 // valid on bit2=1 lanes
            float hp = __shfl_xor(h, 1, 64);    // partner unit's h
            if (wrt)
                *(__half2*)(&hist[j][chn * 160 + ua]) = __floats2half2_rn(h, hp);
            __syncthreads();
        }

        // flush group to flat (coalesced; one vmcnt drain at next barrier)
        {
            int fj = tid >> 5;
            int fch = (tid >> 4) & 1;
            int ck = tid & 15;
            int s = go * 16 + fj;
            int ts = dir ? (255 - s) : s;
            uint4 v = *(const uint4*)(&hist[fj][fch * 160 + ck * 8]);
            *(uint4*)(flat + (long)(b0 + fch) * 65536 + (long)ts * 256 + dir * 128 + ck * 8) = v;
        }
        __syncthreads();
    }
}

// ---- FC1 MFMA split-K: z[256][128] += flat16 @ fc1_w16^T --------------------------
__global__ __launch_bounds__(256) void fc1m_k(const __half* __restrict__ flat,
                                              const __half* __restrict__ wp,
                                              float* __restrict__ z) {
    int tid = threadIdx.x;
    int lane = tid & 63;
    int wv = tid >> 6;
    int l15 = lane & 15;
    int g = lane >> 4;
    int m0 = blockIdx.x * 64 + wv * 16;
    long k0 = (long)blockIdx.y * 1024;

    f4_t acc[8];
#pragma unroll
    for (int nt = 0; nt < 8; nt++)
#pragma unroll
        for (int r = 0; r < 4; r++) acc[nt][r] = 0.f;

    for (int c = 0; c < 32; c++) {
        long chunk = (k0 >> 5) + c;
        H8 af;
        af.u = *(const uint4*)(flat + (long)(m0 + l15) * 65536 + k0 + c * 32 + g * 8);
#pragma unroll
        for (int nt = 0; nt < 8; nt++) {
            H8 bw;
            bw.u = *(const uint4*)(wp + ((chunk * 4 + g) * 128 + nt * 16 + l15) * 8);
            acc[nt] = __builtin_amdgcn_mfma_f32_16x16x32_f16(af.v, bw.v, acc[nt], 0, 0, 0);
        }
    }
#pragma unroll
    for (int nt = 0; nt < 8; nt++)
#pragma unroll
        for (int r = 0; r < 4; r++)
            atomicAdd(&z[(m0 + g * 4 + r) * 128 + nt * 16 + l15], acc[nt][r]);
}

__global__ void zero_k(float* __restrict__ p, int n) {
    int i = blockIdx.x * 256 + threadIdx.x;
    if (i < n) p[i] = 0.f;
}

// ---- head -------------------------------------------------------------------------
__global__ __launch_bounds__(256) void head_k(const float* __restrict__ z,
                                              const float* __restrict__ b1,
                                              const float* __restrict__ fsw,
                                              const float* __restrict__ fsb,
                                              float* __restrict__ out) {
    __shared__ float sf[256];
    int r = threadIdx.x;
    float acc = fsb[0];
#pragma unroll
    for (int j4 = 0; j4 < 32; j4++) {
        float4 zv = *(const float4*)&z[r * 128 + j4 * 4];
        float4 bv = *(const float4*)&b1[j4 * 4];
        float4 wv = *(const float4*)&fsw[j4 * 4];
        acc += fmaxf(zv.x + bv.x, 0.f) * wv.x;
        acc += fmaxf(zv.y + bv.y, 0.f) * wv.y;
        acc += fmaxf(zv.z + bv.z, 0.f) * wv.z;
        acc += fmaxf(zv.w + bv.w, 0.f) * wv.w;
    }
    float val = sigmoidf_(acc) * 4.f + 1.f;
    out[16 + r] = val;
    sf[r] = val;
    __syncthreads();
    if (r < 16) {
        float m = 0.f;
#pragma unroll
        for (int f = 0; f < 16; f++) m += sf[r * 16 + f];
        out[r] = m * (1.f / 16.f);
    }
}

extern "C" void kernel_launch(void* const* d_in, const int* in_sizes, int n_in,
                              void* d_out, int out_size, void* d_ws, size_t ws_size,
                              hipStream_t stream) {
    const float* audio = (const float*)d_in[0];
    const float* w0 = (const float*)d_in[2];
    const float* b0 = (const float*)d_in[3];
    const float* w1 = (const float*)d_in[4];
    const float* b1 = (const float*)d_in[5];
    const float* w2 = (const float*)d_in[6];
    const float* b2 = (const float*)d_in[7];
    const float* w3 = (const float*)d_in[8];
    const float* b3 = (const float*)d_in[9];
    const float* Wih_f = (const float*)d_in[10];
    const float* Whh_f = (const float*)d_in[11];
    const float* bih_f = (const float*)d_in[12];
    const float* bhh_f = (const float*)d_in[13];
    const float* Wih_b = (const float*)d_in[14];
    const float* Whh_b = (const float*)d_in[15];
    const float* bih_b = (const float*)d_in[16];
    const float* bhh_b = (const float*)d_in[17];
    const float* fc1_w = (const float*)d_in[18];
    const float* fc1_b = (const float*)d_in[19];
    const float* fs_w = (const float*)d_in[20];
    const float* fs_b = (const float*)d_in[21];
    float* out = (float*)d_out;

    char* ws = (char*)d_ws;
    // lifetimes: out1 dies before Gf; out0 dies before flat16; Gf/Gb die before fc1p
    __half* Gf    = (__half*)(ws);                    // 67.1 MB (transposed layout)
    __half* out1  = (__half*)(ws);                    // 37.7 MB (pre-Gf)
    __half* fc1p  = (__half*)(ws);                    // 16.8 MB (post-lstm, in Gf)
    __half* Gb    = (__half*)(ws + 67108864);         // 67.1 MB
    __half* flat16= (__half*)(ws + 134217728);        // 33.6 MB
    __half* out0  = (__half*)(ws + 134217728);        // 56.6 MB (pre-flat16)
    __half* X     = (__half*)(ws + 201326592);        // 16.8 MB
    __half* out2  = (__half*)(ws + 218103808);        // 25.2 MB
    char* rd = ws + 243269632;
    float*  w0t   = (float*)(rd);
    __half* w1p   = (__half*)(rd + 1024);
    __half* w2p   = (__half*)(rd + 10240);
    __half* w3p   = (__half*)(rd + 47104);
    __half* wfp   = (__half*)(rd + 194560);
    __half* wbp   = (__half*)(rd + 325632);
    __half* whhfp = (__half*)(rd + 456704);
    __half* whhbp = (__half*)(rd + 587776);
    float*  zbuf  = (float*)(rd + 718848);

    // fused weight prep (1 launch)
    prep_k<<<1403, 256, 0, stream>>>(w0, w1, w2, w3, Wih_f, Wih_b, Whh_f, Whh_b,
                                     w0t, w1p, w2p, w3p, wfp, wbp, whhfp, whhbp);

    // conv chain (NHWC f16)
    conv0_k<<<6912, 256, 0, stream>>>(audio, w0t, b0, out0);
    convM_k<16, 32, 27, 9, 16><<<9216, 256, 0, stream>>>(out0, w1p, b1, out1);
    convM_k<32, 64, 9, 3, 32><<<3072, 256, 0, stream>>>(out1, w2p, b2, out2);
    convM_k<64, 128, 3, 1, 32><<<1024, 256, 0, stream>>>(out2, w3p, b3, X);

    // gates, both directions, transposed G output
    gates_k<<<dim3(512, 4, 2), 256, 0, stream>>>(X, wfp, wbp, bih_f, bhh_f,
                                                 bih_b, bhh_b, Gf, Gb);

    // recurrence (2 chains/block; barrier-clean inner groups)
    lstm_k<<<256, 512, 0, stream>>>(Gf, Gb, whhfp, whhbp, flat16);

    // FC head: pack fc1_w (into dead Gf region), split-K MFMA, head
    pack_wf16<<<32768, 256, 0, stream>>>(fc1_w, fc1p, 128, 65536, 32, 65536, 1, 0, 8388608);
    zero_k<<<128, 256, 0, stream>>>(zbuf, 256 * 128);
    fc1m_k<<<dim3(4, 64), 256, 0, stream>>>(flat16, fc1p, zbuf);
    head_k<<<1, 256, 0, stream>>>(zbuf, fc1_b, fs_w, fs_b, out);
}

// Round 10
// 547.670 us; speedup vs baseline: 1.2024x; 1.0114x over previous
//
#include <hip/hip_runtime.h>
#include <hip/hip_fp16.h>

#define BF 256
#define TSTEPS 256

typedef _Float16 h8_t __attribute__((ext_vector_type(8)));
typedef _Float16 h4_t __attribute__((ext_vector_type(4)));
typedef float f4_t __attribute__((ext_vector_type(4)));

union H8 { uint4 u; h8_t v; };
union H4 { uint2 u; h4_t v; };
union U2H4 { uint2 u; __half h[4]; };

static __device__ __forceinline__ float sigmoidf_(float x) {
    return 1.f / (1.f + __expf(-x));
}
static __device__ __forceinline__ float tanhf_(float x) {
    return 1.f - 2.f / (__expf(2.f * x) + 1.f);
}

// ---- pack helper: f16 MFMA operand layout -----------------------------------------
static __device__ __forceinline__ void pack_one(const float* __restrict__ src,
                                                __half* __restrict__ dst,
                                                int OC, int IC, int KS,
                                                int oc_str, int ic_str, int k_str, int i) {
    int grp = KS / 4;
    int j = i % grp;
    int oc = (i / grp) % OC;
    int g = (i / (grp * OC)) & 3;
    int chunk = i / (grp * OC * 4);
    int CPK = IC / KS;
    int cc = chunk % CPK;
    int khw = chunk / CPK;
    int ic = cc * KS + g * grp + j;
    dst[i] = __float2half(src[(long)oc * oc_str + (long)ic * ic_str + khw * k_str]);
}

// ---- fused weight prep ------------------------------------------------------------
__global__ __launch_bounds__(256) void prep_k(
        const float* __restrict__ w0, const float* __restrict__ w1,
        const float* __restrict__ w2, const float* __restrict__ w3,
        const float* __restrict__ Wihf, const float* __restrict__ Wihb,
        const float* __restrict__ Whhf, const float* __restrict__ Whhb,
        float* __restrict__ w0t, __half* __restrict__ w1p,
        __half* __restrict__ w2p, __half* __restrict__ w3p,
        __half* __restrict__ wfp, __half* __restrict__ wbp,
        __half* __restrict__ whhfp, __half* __restrict__ whhbp) {
    int i = blockIdx.x * 256 + threadIdx.x;
    if (i < 144) { int oc = i / 9, rem = i % 9; w0t[rem * 16 + oc] = w0[i]; return; }
    i -= 144;
    if (i < 4608) { pack_one(w1, w1p, 32, 16, 16, 144, 9, 1, i); return; }
    i -= 4608;
    if (i < 18432) { pack_one(w2, w2p, 64, 32, 32, 288, 9, 1, i); return; }
    i -= 18432;
    if (i < 73728) { pack_one(w3, w3p, 128, 64, 32, 576, 9, 1, i); return; }
    i -= 73728;
    if (i < 65536) { pack_one(Wihf, wfp, 512, 128, 32, 128, 1, 0, i); return; }
    i -= 65536;
    if (i < 65536) { pack_one(Wihb, wbp, 512, 128, 32, 128, 1, 0, i); return; }
    i -= 65536;
    if (i < 65536) { pack_one(Whhf, whhfp, 512, 128, 32, 128, 1, 0, i); return; }
    i -= 65536;
    if (i < 65536) { pack_one(Whhb, whhbp, 512, 128, 32, 128, 1, 0, i); return; }
}

__global__ void pack_wf16(const float* __restrict__ src, __half* __restrict__ dst,
                          int OC, int IC, int KS,
                          int oc_str, int ic_str, int k_str, int total) {
    int i = blockIdx.x * 256 + threadIdx.x;
    if (i >= total) return;
    pack_one(src, dst, OC, IC, KS, oc_str, ic_str, k_str, i);
}

// ---- conv0: 1->16 ch, VALU, NHWC f16 out ------------------------------------------
__global__ __launch_bounds__(256) void conv0_k(const float* __restrict__ in,
                                               const float* __restrict__ wT,
                                               const float* __restrict__ bias,
                                               __half* __restrict__ out) {
    __shared__ float wsm[9][16];
    __shared__ float bs[16];
    int tid = threadIdx.x;
    if (tid < 144) wsm[tid / 16][tid % 16] = wT[tid];
    if (tid < 16) bs[tid] = bias[tid];
    __syncthreads();
    int gid = blockIdx.x * 256 + tid;
    int ow = gid % 27;
    int t = (gid / 27) % 256;
    int bf = gid / (27 * 256);
    float acc[16];
#pragma unroll
    for (int o = 0; o < 16; o++) acc[o] = bs[o];
    int iw0 = ow * 3 - 1;
#pragma unroll
    for (int kh = 0; kh < 3; kh++) {
        int tt = t + kh - 1;
        if ((unsigned)tt >= 256u) continue;
        const float* ip = in + ((long)bf * 256 + tt) * 81;
#pragma unroll
        for (int kw = 0; kw < 3; kw++) {
            int iw = iw0 + kw;
            if ((unsigned)iw >= 81u) continue;
            float x = ip[iw];
#pragma unroll
            for (int o = 0; o < 16; o++) acc[o] += x * wsm[kh * 3 + kw][o];
        }
    }
    __half2* op = (__half2*)(out + (long)gid * 16);
#pragma unroll
    for (int o = 0; o < 8; o++)
        op[o] = __floats2half2_rn(fmaxf(acc[2 * o], 0.f), fmaxf(acc[2 * o + 1], 0.f));
}

// ---- MFMA implicit-GEMM conv, MT m-tiles per wave (B amortized over MT) -----------
template<int IC, int OC, int WIN, int WOUT, int KS, int MT>
__global__ __launch_bounds__(256) void convM_k(const __half* __restrict__ in,
                                               const __half* __restrict__ wp,
                                               const float* __restrict__ bias,
                                               __half* __restrict__ out) {
    constexpr int NT = OC / 16;
    constexpr int CPK = IC / KS;
    constexpr int NCHUNK = 9 * CPK;
    constexpr int GRP = KS / 4;
    int tid = threadIdx.x;
    int lane = tid & 63;
    int wv = tid >> 6;
    int l15 = lane & 15;
    int g = lane >> 4;
    int mbase = blockIdx.x * (4 * MT * 16) + wv * MT * 16;

    int owA[MT], tA[MT], bfA[MT];
#pragma unroll
    for (int mt = 0; mt < MT; mt++) {
        int m = mbase + mt * 16 + l15;
        owA[mt] = m % WOUT;
        tA[mt] = (m / WOUT) % 256;
        bfA[mt] = m / (WOUT * 256);
    }

    f4_t acc[MT][NT];
#pragma unroll
    for (int mt = 0; mt < MT; mt++)
#pragma unroll
        for (int nt = 0; nt < NT; nt++)
#pragma unroll
            for (int r = 0; r < 4; r++) acc[mt][nt][r] = 0.f;

#pragma unroll
    for (int chunk = 0; chunk < NCHUNK; chunk++) {
        int khw = chunk / CPK, cc = chunk % CPK;
        int kh = khw / 3;
        int kw = khw - kh * 3;
        if constexpr (KS == 32) {
            H8 af[MT];
#pragma unroll
            for (int mt = 0; mt < MT; mt++) {
                int tt = tA[mt] + kh - 1;
                int iw = owA[mt] * 3 + kw - 1;
                bool ok = ((unsigned)tt < 256u) && ((unsigned)iw < (unsigned)WIN);
                long aoff = ok ? (((long)(bfA[mt] * 256 + tt) * WIN + iw) * IC
                                  + cc * KS + g * GRP) : 0;
                af[mt].u = *(const uint4*)(in + aoff);
                if (!ok) af[mt].u = make_uint4(0u, 0u, 0u, 0u);
            }
#pragma unroll
            for (int nt = 0; nt < NT; nt++) {
                H8 bf8;
                bf8.u = *(const uint4*)(wp + ((long)(chunk * 4 + g) * OC + nt * 16 + l15) * GRP);
#pragma unroll
                for (int mt = 0; mt < MT; mt++)
                    acc[mt][nt] = __builtin_amdgcn_mfma_f32_16x16x32_f16(af[mt].v, bf8.v,
                                                                         acc[mt][nt], 0, 0, 0);
            }
        } else {
            H4 af[MT];
#pragma unroll
            for (int mt = 0; mt < MT; mt++) {
                int tt = tA[mt] + kh - 1;
                int iw = owA[mt] * 3 + kw - 1;
                bool ok = ((unsigned)tt < 256u) && ((unsigned)iw < (unsigned)WIN);
                long aoff = ok ? (((long)(bfA[mt] * 256 + tt) * WIN + iw) * IC
                                  + cc * KS + g * GRP) : 0;
                af[mt].u = *(const uint2*)(in + aoff);
                if (!ok) af[mt].u = make_uint2(0u, 0u);
            }
#pragma unroll
            for (int nt = 0; nt < NT; nt++) {
                H4 bf4;
                bf4.u = *(const uint2*)(wp + ((long)(chunk * 4 + g) * OC + nt * 16 + l15) * GRP);
#pragma unroll
                for (int mt = 0; mt < MT; mt++)
                    acc[mt][nt] = __builtin_amdgcn_mfma_f32_16x16x16f16(af[mt].v, bf4.v,
                                                                        acc[mt][nt], 0, 0, 0);
            }
        }
    }
#pragma unroll
    for (int mt = 0; mt < MT; mt++) {
        int orow = mbase + mt * 16 + g * 4;
#pragma unroll
        for (int nt = 0; nt < NT; nt++) {
            int oc = nt * 16 + l15;
            float b = bias[oc];
#pragma unroll
            for (int r = 0; r < 4; r++) {
                float v = fmaxf(acc[mt][nt][r] + b, 0.f);
                out[(long)(orow + r) * OC + oc] = __float2half(v);
            }
        }
    }
}

// ---- gates MFMA GEMM, TRANSPOSED output G'[(b*512+gate)*256 + tidx] ---------------
__global__ __launch_bounds__(256) void gates_k(const __half* __restrict__ X,
                                               const __half* __restrict__ wpf,
                                               const __half* __restrict__ wpb,
                                               const float* __restrict__ bf1,
                                               const float* __restrict__ bf2,
                                               const float* __restrict__ bb1,
                                               const float* __restrict__ bb2,
                                               __half* __restrict__ Gf,
                                               __half* __restrict__ Gb) {
    int dir = blockIdx.z;
    const __half* wp = dir ? wpb : wpf;
    const float* b1 = dir ? bb1 : bf1;
    const float* b2 = dir ? bb2 : bf2;
    __half* G = dir ? Gb : Gf;
    int tid = threadIdx.x;
    int lane = tid & 63;
    int wv = tid >> 6;
    int l15 = lane & 15;
    int g = lane >> 4;
    long r0 = (long)blockIdx.x * 128 + wv * 32;
    int n0 = blockIdx.y * 128;

    f4_t acc[2][8];
#pragma unroll
    for (int s = 0; s < 2; s++)
#pragma unroll
        for (int nt = 0; nt < 8; nt++)
#pragma unroll
            for (int r = 0; r < 4; r++) acc[s][nt][r] = 0.f;

#pragma unroll
    for (int chunk = 0; chunk < 4; chunk++) {
        H8 a0, a1;
        a0.u = *(const uint4*)(X + (r0 + l15) * 128 + chunk * 32 + g * 8);
        a1.u = *(const uint4*)(X + (r0 + 16 + l15) * 128 + chunk * 32 + g * 8);
#pragma unroll
        for (int nt = 0; nt < 8; nt++) {
            H8 bw;
            bw.u = *(const uint4*)(wp + ((long)(chunk * 4 + g) * 512 + n0 + nt * 16 + l15) * 8);
            acc[0][nt] = __builtin_amdgcn_mfma_f32_16x16x32_f16(a0.v, bw.v, acc[0][nt], 0, 0, 0);
            acc[1][nt] = __builtin_amdgcn_mfma_f32_16x16x32_f16(a1.v, bw.v, acc[1][nt], 0, 0, 0);
        }
    }
    int b = (int)(r0 >> 8);
#pragma unroll
    for (int nt = 0; nt < 8; nt++) {
        int col = n0 + nt * 16 + l15;
        float bias = b1[col] + b2[col];
        long base = ((long)b * 512 + col) * 256;
#pragma unroll
        for (int s = 0; s < 2; s++) {
            int tb = (int)(r0 & 255) + s * 16 + g * 4;
            U2H4 pk;
            if (!dir) {
#pragma unroll
                for (int r = 0; r < 4; r++) pk.h[r] = __float2half(acc[s][nt][r] + bias);
                *(uint2*)(G + base + tb) = pk.u;
            } else {
#pragma unroll
                for (int r = 0; r < 4; r++) pk.h[3 - r] = __float2half(acc[s][nt][r] + bias);
                *(uint2*)(G + base + (252 - tb)) = pk.u;
            }
        }
    }
}

// ---- LSTM recurrence: 256 blocks x 512 thr, 2 chains/block ------------------------
// Inner 16-step groups have NO global memory ops: G staged in registers per group,
// h history in a 16-row LDS window (chain stride 160 halves -> disjoint banks),
// flat flushed once per group (1 vmcnt drain / 16 steps).
__global__ __launch_bounds__(512, 2) void lstm_k(const __half* __restrict__ Gf,
                                                 const __half* __restrict__ Gb,
                                                 const __half* __restrict__ whhfp,
                                                 const __half* __restrict__ whhbp,
                                                 __half* __restrict__ flat) {
    int bid = blockIdx.x;
    int dir = bid >> 7;
    int b0 = (bid & 127) * 2;
    const __half* G = dir ? Gb : Gf;
    const __half* wp = dir ? whhbp : whhfp;
    int tid = threadIdx.x;
    int w = tid >> 6;
    int lane = tid & 63;
    int l15 = lane & 15;
    int g2 = lane >> 4;
    int chn = l15 >> 3;
    int r = l15 & 3;
    int bit2 = (l15 >> 2) & 1;
    int ua = w * 16 + g2 * 4 + r;
    bool wrt = bit2 && ((r & 1) == 0);

    // Whh A-frags: 4 classes x 4 k-chunks = 64 regs/lane
    H8 afr[4][4];
#pragma unroll
    for (int k = 0; k < 4; k++) {
        int gate = k * 128 + w * 16 + l15;
#pragma unroll
        for (int c = 0; c < 4; c++)
            afr[k][c].u = *(const uint4*)(wp + ((long)((c * 4 + g2) * 512 + gate)) * 8);
    }

    // 16-step h window; chain stride 160 halves (80 words = 16 banks) -> no conflicts
    __shared__ __align__(16) __half hist[16][320];
    if (tid < 160) { hist[15][tid] = __float2half(0.f);
                     hist[15][160 + tid] = __float2half(0.f); }
    __syncthreads();

    // this lane's two gate-class rows in transposed G
    const __half* gp0 = G + (((long)(b0 + chn) * 512) + bit2 * 256 + ua) * 256;
    const __half* gp1 = gp0 + 128 * 256;

    float cst = 0.f;
    float ma = bit2 ? 2.f : 1.f;
    float mb = ma;
    float cb = bit2 ? -1.f : 0.f;
    const f4_t zero4 = {0.f, 0.f, 0.f, 0.f};

    for (int go = 0; go < 16; go++) {
        // stage this group's 16 gate pre-activations per class (registers)
        H8 gA0, gA1, gB0, gB1;
        gA0.u = *(const uint4*)(gp0 + go * 16);
        gA1.u = *(const uint4*)(gp0 + go * 16 + 8);
        gB0.u = *(const uint4*)(gp1 + go * 16);
        gB1.u = *(const uint4*)(gp1 + go * 16 + 8);

#pragma unroll
        for (int j = 0; j < 16; j++) {
            int rs = (j + 15) & 15;
            H8 bfr[4];
#pragma unroll
            for (int c = 0; c < 4; c++)
                bfr[c].u = *(const uint4*)(&hist[rs][chn * 160 + c * 32 + g2 * 8]);

            f4_t acc[4];
#pragma unroll
            for (int k = 0; k < 4; k++)
                acc[k] = __builtin_amdgcn_mfma_f32_16x16x32_f16(afr[k][0].v, bfr[0].v,
                                                                zero4, 0, 0, 0);
#pragma unroll
            for (int c = 1; c < 4; c++)
#pragma unroll
                for (int k = 0; k < 4; k++)
                    acc[k] = __builtin_amdgcn_mfma_f32_16x16x32_f16(afr[k][c].v, bfr[c].v,
                                                                    acc[k], 0, 0, 0);
            f4_t aA, aB;
#pragma unroll
            for (int e = 0; e < 4; e++) {
                aA[e] = bit2 ? acc[2][e] : acc[0][e];
                aB[e] = bit2 ? acc[3][e] : acc[1][e];
            }
            float loA = (r & 1) ? aA[1] : aA[0];
            float hiA = (r & 1) ? aA[3] : aA[2];
            float eA = (r & 2) ? hiA : loA;
            float loB = (r & 1) ? aB[1] : aB[0];
            float hiB = (r & 1) ? aB[3] : aB[2];
            float eB = (r & 2) ? hiB : loB;

            float ga = (float)((j < 8) ? gA0.v[j & 7] : gA1.v[j & 7]);
            float gb = (float)((j < 8) ? gB0.v[j & 7] : gB1.v[j & 7]);
            float za = eA + ga;
            float zb = eB + gb;
            float sa = sigmoidf_(ma * za);
            float fa = sa * mb + cb;            // bit2=0: sigmoid(i); bit2=1: tanh(g)
            float sb = sigmoidf_(zb);           // bit2=0: sigmoid(f); bit2=1: sigmoid(o)
            float grecv = __shfl_xor(fa, 4, 64);
            float cn = sb * cst + fa * grecv;   // valid on bit2=0 lanes
            cst = cn;
            float tc = tanhf_(cn);
            float tcr = __shfl_xor(tc, 4, 64);  // bit2=1 receives tanh(c')
            float h = sb * tcr;                 // valid on bit2=1 lanes
            float hp = __shfl_xor(h, 1, 64);    // partner unit's h
            if (wrt)
                *(__half2*)(&hist[j][chn * 160 + ua]) = __floats2half2_rn(h, hp);
            __syncthreads();
        }

        // flush group to flat (coalesced; one vmcnt drain at next barrier)
        {
            int fj = tid >> 5;
            int fch = (tid >> 4) & 1;
            int ck = tid & 15;
            int s = go * 16 + fj;
            int ts = dir ? (255 - s) : s;
            uint4 v = *(const uint4*)(&hist[fj][fch * 160 + ck * 8]);
            *(uint4*)(flat + (long)(b0 + fch) * 65536 + (long)ts * 256 + dir * 128 + ck * 8) = v;
        }
        __syncthreads();
    }
}

// ---- FC1 MFMA split-K: z[256][128] += flat16 @ fc1_w16^T --------------------------
__global__ __launch_bounds__(256) void fc1m_k(const __half* __restrict__ flat,
                                              const __half* __restrict__ wp,
                                              float* __restrict__ z) {
    int tid = threadIdx.x;
    int lane = tid & 63;
    int wv = tid >> 6;
    int l15 = lane & 15;
    int g = lane >> 4;
    int m0 = blockIdx.x * 64 + wv * 16;
    long k0 = (long)blockIdx.y * 1024;

    f4_t acc[8];
#pragma unroll
    for (int nt = 0; nt < 8; nt++)
#pragma unroll
        for (int r = 0; r < 4; r++) acc[nt][r] = 0.f;

    for (int c = 0; c < 32; c++) {
        long chunk = (k0 >> 5) + c;
        H8 af;
        af.u = *(const uint4*)(flat + (long)(m0 + l15) * 65536 + k0 + c * 32 + g * 8);
#pragma unroll
        for (int nt = 0; nt < 8; nt++) {
            H8 bw;
            bw.u = *(const uint4*)(wp + ((chunk * 4 + g) * 128 + nt * 16 + l15) * 8);
            acc[nt] = __builtin_amdgcn_mfma_f32_16x16x32_f16(af.v, bw.v, acc[nt], 0, 0, 0);
        }
    }
#pragma unroll
    for (int nt = 0; nt < 8; nt++)
#pragma unroll
        for (int r = 0; r < 4; r++)
            atomicAdd(&z[(m0 + g * 4 + r) * 128 + nt * 16 + l15], acc[nt][r]);
}

__global__ void zero_k(float* __restrict__ p, int n) {
    int i = blockIdx.x * 256 + threadIdx.x;
    if (i < n) p[i] = 0.f;
}

// ---- head -------------------------------------------------------------------------
__global__ __launch_bounds__(256) void head_k(const float* __restrict__ z,
                                              const float* __restrict__ b1,
                                              const float* __restrict__ fsw,
                                              const float* __restrict__ fsb,
                                              float* __restrict__ out) {
    __shared__ float sf[256];
    int r = threadIdx.x;
    float acc = fsb[0];
#pragma unroll
    for (int j4 = 0; j4 < 32; j4++) {
        float4 zv = *(const float4*)&z[r * 128 + j4 * 4];
        float4 bv = *(const float4*)&b1[j4 * 4];
        float4 wv = *(const float4*)&fsw[j4 * 4];
        acc += fmaxf(zv.x + bv.x, 0.f) * wv.x;
        acc += fmaxf(zv.y + bv.y, 0.f) * wv.y;
        acc += fmaxf(zv.z + bv.z, 0.f) * wv.z;
        acc += fmaxf(zv.w + bv.w, 0.f) * wv.w;
    }
    float val = sigmoidf_(acc) * 4.f + 1.f;
    out[16 + r] = val;
    sf[r] = val;
    __syncthreads();
    if (r < 16) {
        float m = 0.f;
#pragma unroll
        for (int f = 0; f < 16; f++) m += sf[r * 16 + f];
        out[r] = m * (1.f / 16.f);
    }
}

extern "C" void kernel_launch(void* const* d_in, const int* in_sizes, int n_in,
                              void* d_out, int out_size, void* d_ws, size_t ws_size,
                              hipStream_t stream) {
    const float* audio = (const float*)d_in[0];
    const float* w0 = (const float*)d_in[2];
    const float* b0 = (const float*)d_in[3];
    const float* w1 = (const float*)d_in[4];
    const float* b1 = (const float*)d_in[5];
    const float* w2 = (const float*)d_in[6];
    const float* b2 = (const float*)d_in[7];
    const float* w3 = (const float*)d_in[8];
    const float* b3 = (const float*)d_in[9];
    const float* Wih_f = (const float*)d_in[10];
    const float* Whh_f = (const float*)d_in[11];
    const float* bih_f = (const float*)d_in[12];
    const float* bhh_f = (const float*)d_in[13];
    const float* Wih_b = (const float*)d_in[14];
    const float* Whh_b = (const float*)d_in[15];
    const float* bih_b = (const float*)d_in[16];
    const float* bhh_b = (const float*)d_in[17];
    const float* fc1_w = (const float*)d_in[18];
    const float* fc1_b = (const float*)d_in[19];
    const float* fs_w = (const float*)d_in[20];
    const float* fs_b = (const float*)d_in[21];
    float* out = (float*)d_out;

    char* ws = (char*)d_ws;
    // lifetimes: out1 dies before Gf; out0 dies before flat16; Gf/Gb die before fc1p
    __half* Gf    = (__half*)(ws);                    // 67.1 MB (transposed layout)
    __half* out1  = (__half*)(ws);                    // 37.7 MB (pre-Gf)
    __half* fc1p  = (__half*)(ws);                    // 16.8 MB (post-lstm, in Gf)
    __half* Gb    = (__half*)(ws + 67108864);         // 67.1 MB
    __half* flat16= (__half*)(ws + 134217728);        // 33.6 MB
    __half* out0  = (__half*)(ws + 134217728);        // 56.6 MB (pre-flat16)
    __half* X     = (__half*)(ws + 201326592);        // 16.8 MB
    __half* out2  = (__half*)(ws + 218103808);        // 25.2 MB
    char* rd = ws + 243269632;
    float*  w0t   = (float*)(rd);
    __half* w1p   = (__half*)(rd + 1024);
    __half* w2p   = (__half*)(rd + 10240);
    __half* w3p   = (__half*)(rd + 47104);
    __half* wfp   = (__half*)(rd + 194560);
    __half* wbp   = (__half*)(rd + 325632);
    __half* whhfp = (__half*)(rd + 456704);
    __half* whhbp = (__half*)(rd + 587776);
    float*  zbuf  = (float*)(rd + 718848);

    // fused weight prep (1 launch)
    prep_k<<<1403, 256, 0, stream>>>(w0, w1, w2, w3, Wih_f, Wih_b, Whh_f, Whh_b,
                                     w0t, w1p, w2p, w3p, wfp, wbp, whhfp, whhbp);

    // conv chain (NHWC f16), MT m-tiles per wave
    conv0_k<<<6912, 256, 0, stream>>>(audio, w0t, b0, out0);
    convM_k<16, 32, 27, 9, 16, 4><<<2304, 256, 0, stream>>>(out0, w1p, b1, out1);
    convM_k<32, 64, 9, 3, 32, 4><<<768, 256, 0, stream>>>(out1, w2p, b2, out2);
    convM_k<64, 128, 3, 1, 32, 2><<<512, 256, 0, stream>>>(out2, w3p, b3, X);

    // gates, both directions, transposed G output
    gates_k<<<dim3(512, 4, 2), 256, 0, stream>>>(X, wfp, wbp, bih_f, bhh_f,
                                                 bih_b, bhh_b, Gf, Gb);

    // recurrence (2 chains/block; barrier-clean inner groups)
    lstm_k<<<256, 512, 0, stream>>>(Gf, Gb, whhfp, whhbp, flat16);

    // FC head: pack fc1_w (into dead Gf region), split-K MFMA, head
    pack_wf16<<<32768, 256, 0, stream>>>(fc1_w, fc1p, 128, 65536, 32, 65536, 1, 0, 8388608);
    zero_k<<<128, 256, 0, stream>>>(zbuf, 256 * 128);
    fc1m_k<<<dim3(4, 64), 256, 0, stream>>>(flat16, fc1p, zbuf);
    head_k<<<1, 256, 0, stream>>>(zbuf, fc1_b, fs_w, fs_b, out);
}